// Round 11
// baseline (324.099 us; speedup 1.0000x reference)
//
#include <hip/hip_runtime.h>
#include <hip/hip_bf16.h>
#include <stdint.h>

#define T_SEQ 336
#define NKT   11        // K-tiles of 32 (336 -> 352; tail zeroed in LDS, apack zero-padded)
#define P_LEN 720
#define NM16  48        // 16-row p-blocks in apack (768 rows, zero-padded)
#define C_LEN 1782
#define NB    64
#define CT    64        // cols per panel (256B row segments, 128B-aligned)
#define NPANEL 7        // panels per block; 4 blocks per batch -> 28 col-tiles
#define SPITCH 384      // LDS row pitch in shorts (48 k8-slots of 8): 768B rows

typedef __attribute__((ext_vector_type(4))) float f32x4;
typedef __attribute__((ext_vector_type(8))) short s16x8;

__device__ __forceinline__ unsigned short f2bf(float f) {
  unsigned int u = __builtin_bit_cast(unsigned int, f);
  u += 0x7FFFu + ((u >> 16) & 1u);   // RNE
  return (unsigned short)(u >> 16);
}

// Weff[p,k] = Ws[p,k] + 0.2*sum_{t in win(k)} (Wt-Ws)[p,t], packed in MFMA
// A-fragment order: block m16*NKT+kt holds 64 lanes x 16B; lane lg*16+l16
// carries W[m16*16+l16][kt*32+lg*8+j], j=0..7. Zero-padded p>=720, k>=336.
__global__ __launch_bounds__(64) void prep_w(
    const float* __restrict__ Ws, const float* __restrict__ bs,
    const float* __restrict__ Wt, const float* __restrict__ bt,
    unsigned short* __restrict__ apack, float* __restrict__ bias) {
  const int p   = blockIdx.x;          // 0..767
  const int tid = threadIdx.x;         // 0..63
  if (tid < NKT * 4) {
    const int kt = tid >> 2;
    const int lg = tid & 3;
    const float* wsr = Ws + (size_t)p * T_SEQ;
    const float* wtr = Wt + (size_t)p * T_SEQ;
    union { s16x8 v; unsigned short u[8]; } pk;
#pragma unroll
    for (int j = 0; j < 8; ++j) {
      const int k = kt * 32 + lg * 8 + j;
      float val = 0.f;
      if (p < P_LEN && k < T_SEQ) {
        float d;
        if (k == 0) {
          d = 3.f*(wtr[0]-wsr[0]) + 2.f*(wtr[1]-wsr[1]) + (wtr[2]-wsr[2]);
        } else if (k == T_SEQ-1) {
          d = 3.f*(wtr[T_SEQ-1]-wsr[T_SEQ-1]) + 2.f*(wtr[T_SEQ-2]-wsr[T_SEQ-2])
              + (wtr[T_SEQ-3]-wsr[T_SEQ-3]);
        } else {
          int lo = (k-2 < 0) ? 0 : k-2;
          int hi = (k+2 > T_SEQ-1) ? T_SEQ-1 : k+2;
          d = 0.f;
          for (int t = lo; t <= hi; ++t) d += wtr[t]-wsr[t];
        }
        val = wsr[k] + 0.2f*d;
      }
      pk.u[j] = f2bf(val);
    }
    const int m16 = p >> 4;
    const int l16 = p & 15;
    *(s16x8*)&apack[(size_t)(((m16*NKT + kt) * 64) + lg*16 + l16) * 8] = pk.v;
  }
  if (tid == 0 && p < P_LEN) bias[p] = bs[p] + bt[p];
}

// O[b,p,c] = relu( sum_k Weff[p,k] * X[b,k,c] + bias[p] )
// Persistent: 256 blocks (1/CU), each owns (batch b, 7 consecutive 64-col
// panels); 4 blocks per b, XCD-pinned. Per panel: stage(p+1) into LDS buf^1
// (coalesced 256B/instr fp32 loads -> cvt_pk -> swizzled ds_write) overlapped
// with compute(p) from buf (3 mp x 11 kt x [2 L2-hot A-loads + 4 swizzled
// conflict-free ds_read_b128 + 8 MFMA] + per-mp stores); ONE barrier/panel.
// LDS logical (c,k8) at short-offset c*384 + (k8 ^ (c&7))*8  -> reads 2-way-free.
__global__ __launch_bounds__(512, 2) void gemm_kernel(
    const float* __restrict__ x, const unsigned short* __restrict__ apack,
    const float* __restrict__ bias, float* __restrict__ out) {
  __shared__ __align__(16) unsigned short Bp[2][CT * SPITCH];   // 2 x 49152 B

  // 256 blocks: XCD = bid&7 hosts b in [xcd*8, xcd*8+8), 4 blocks per b
  const int bid = blockIdx.x;
  const int xcd = bid & 7;
  const int idx = bid >> 3;            // 0..31
  const int b   = xcd * 8 + (idx >> 2);
  const int ct0 = (idx & 3) * NPANEL;  // first col-tile (64-wide) of this block

  const int tid  = threadIdx.x;
  const int lane = tid & 63;
  const int wid  = tid >> 6;           // 0..7
  const int l16  = lane & 15;
  const int lg   = lane >> 4;

  const float* xb = x + (size_t)b * T_SEQ * C_LEN;
  const s16x8* ap = (const s16x8*)apack;

  // ---- zero logical k8-slots 42..47 (k 336..383) in both buffers ----
  {
    const s16x8 z = {};
    for (int i = tid; i < 2 * CT * 6; i += 512) {
      const int bf = i / (CT * 6);
      const int r  = i % (CT * 6);
      const int c  = r / 6;
      const int s  = 42 + r % 6;
      *(s16x8*)&Bp[bf][c * SPITCH + ((s ^ (c & 7)) << 3)] = z;
    }
  }

  // ---- staging: panel pp -> buffer pp&1 ----
  // thread (cl 0..63, kq 0..6): column cl, k-range [kq*48, +48); loads are
  // 64-lane consecutive-c = 256B/instr coalesced. 6 swizzled ds_write_b128.
  auto stage = [&](int pp) {
    if (tid < 448) {
      const int cl = tid & 63;
      const int kq = tid >> 6;         // 0..6, 7*48 = 336 exact
      int c = (ct0 + pp) * CT + cl;
      if (c > C_LEN - 1) c = C_LEN - 1;          // dup cols masked at store
      float f[48];
#pragma unroll
      for (int i = 0; i < 48; ++i)
        f[i] = xb[(size_t)(kq * 48 + i) * C_LEN + c];
      union { uint32_t dw[24]; s16x8 v[6]; } u;
#pragma unroll
      for (int h = 0; h < 24; ++h) {
        uint32_t rr;
        asm("v_cvt_pk_bf16_f32 %0, %1, %2"
            : "=v"(rr) : "v"(f[2*h]), "v"(f[2*h+1]));
        u.dw[h] = rr;
      }
      unsigned short* dst = &Bp[pp & 1][cl * SPITCH];
#pragma unroll
      for (int q = 0; q < 6; ++q)
        *(s16x8*)(dst + (((kq * 6 + q) ^ (cl & 7)) << 3)) = u.v[q];
    }
  };

  stage(0);
  __syncthreads();

  const size_t ob = (size_t)b * P_LEN * C_LEN;

#pragma unroll 1
  for (int p = 0; p < NPANEL; ++p) {
    if (p + 1 < NPANEL) stage(p + 1);          // writes buf^1; no sync needed
    const unsigned short* B = &Bp[p & 1][0];
    const int c0 = (ct0 + p) * CT;

#pragma unroll 1
    for (int mp = 0; mp < 3; ++mp) {
      const int m16a = mp * 16 + wid * 2;      // covers m16 0..47
      float bv[2][4];
#pragma unroll
      for (int m = 0; m < 2; ++m) {
        const int pb0 = (m16a + m) * 16 + lg * 4;
#pragma unroll
        for (int r = 0; r < 4; ++r)
          bv[m][r] = (pb0 + r < P_LEN) ? bias[pb0 + r] : 0.f;
      }

      f32x4 acc[2][4] = {};
#pragma unroll
      for (int kt = 0; kt < NKT; ++kt) {
        const s16x8 af0 = ap[(size_t)((m16a)     * NKT + kt) * 64 + lane];
        const s16x8 af1 = ap[(size_t)((m16a + 1) * NKT + kt) * 64 + lane];
        s16x8 bf[4];
#pragma unroll
        for (int n = 0; n < 4; ++n) {
          const int c = n * 16 + l16;
          bf[n] = *(const s16x8*)&B[c * SPITCH + ((((kt << 2) + lg) ^ (c & 7)) << 3)];
        }
#pragma unroll
        for (int n = 0; n < 4; ++n) {
          acc[0][n] = __builtin_amdgcn_mfma_f32_16x16x32_bf16(
              af0, bf[n], acc[0][n], 0, 0, 0);
          acc[1][n] = __builtin_amdgcn_mfma_f32_16x16x32_bf16(
              af1, bf[n], acc[1][n], 0, 0, 0);
        }
      }

      // per-mp stores: spread the write stream across the panel's compute.
      // C/D layout: row = lg*4 + r (-> p), col = l16 (-> c)
#pragma unroll
      for (int m = 0; m < 2; ++m) {
        const int m16 = m16a + m;
        if (m16 < 45) {                        // p < 720, uniform per fragment
          const int pb0 = m16 * 16 + lg * 4;
#pragma unroll
          for (int n = 0; n < 4; ++n) {
            const int cc = c0 + n * 16 + l16;
            if (cc < C_LEN) {
#pragma unroll
              for (int r = 0; r < 4; ++r) {
                float vv = acc[m][n][r] + bv[m][r];
                out[ob + (size_t)(pb0 + r) * C_LEN + cc] = fmaxf(vv, 0.f);
              }
            }
          }
        }
      }
    }
    __syncthreads();   // buf^1 staged & buf reads done -> safe to swap
  }
}

extern "C" void kernel_launch(void* const* d_in, const int* in_sizes, int n_in,
                              void* d_out, int out_size, void* d_ws, size_t ws_size,
                              hipStream_t stream) {
  (void)in_sizes; (void)n_in; (void)out_size; (void)ws_size;
  const float* x  = (const float*)d_in[0];
  const float* Ws = (const float*)d_in[1];
  const float* bs = (const float*)d_in[2];
  const float* Wt = (const float*)d_in[3];
  const float* bt = (const float*)d_in[4];
  float* out = (float*)d_out;

  // ws: Apack (48*11 blocks * 1KB = 540672 B) then bias (720 f32)
  unsigned short* apack = (unsigned short*)d_ws;
  float* biasp = (float*)((char*)d_ws + (size_t)NM16 * NKT * 1024);

  prep_w<<<dim3(768), dim3(64), 0, stream>>>(Ws, bs, Wt, bt, apack, biasp);
  gemm_kernel<<<dim3(256), dim3(512), 0, stream>>>(x, apack, biasp, out);
}

// Round 12
// 195.912 us; speedup vs baseline: 1.6543x; 1.6543x over previous
//
#include <hip/hip_runtime.h>
#include <hip/hip_bf16.h>
#include <stdint.h>

#define T_SEQ 336
#define NKT   11        // K-tiles of 32 (336 -> 352; tail zeroed in LDS, apack zero-padded)
#define P_LEN 720
#define NM16  48        // 16-row p-blocks in apack (768 rows, zero-padded)
#define C_LEN 1782
#define NB    64
#define CTILE 112       // cols per block (16 tiles -> 1792, clamped/masked)
#define NCT   16
#define BPITCH 360      // LDS row pitch (bf16); 80640 B total -> 2 blocks/CU

typedef __attribute__((ext_vector_type(4))) float f32x4;
typedef __attribute__((ext_vector_type(8))) short s16x8;

__device__ __forceinline__ unsigned short f2bf(float f) {
  unsigned int u = __builtin_bit_cast(unsigned int, f);
  u += 0x7FFFu + ((u >> 16) & 1u);   // RNE
  return (unsigned short)(u >> 16);
}

// Weff[p,k] = Ws[p,k] + 0.2*sum_{t in win(k)} (Wt-Ws)[p,t], packed in MFMA
// A-fragment order: block m16*NKT+kt holds 64 lanes x 16B; lane lg*16+l16
// carries W[m16*16+l16][kt*32+lg*8+j], j=0..7. Zero-padded p>=720, k>=336.
__global__ __launch_bounds__(64) void prep_w(
    const float* __restrict__ Ws, const float* __restrict__ bs,
    const float* __restrict__ Wt, const float* __restrict__ bt,
    unsigned short* __restrict__ apack, float* __restrict__ bias) {
  const int p   = blockIdx.x;          // 0..767
  const int tid = threadIdx.x;         // 0..63
  if (tid < NKT * 4) {
    const int kt = tid >> 2;
    const int lg = tid & 3;
    const float* wsr = Ws + (size_t)p * T_SEQ;
    const float* wtr = Wt + (size_t)p * T_SEQ;
    union { s16x8 v; unsigned short u[8]; } pk;
#pragma unroll
    for (int j = 0; j < 8; ++j) {
      const int k = kt * 32 + lg * 8 + j;
      float val = 0.f;
      if (p < P_LEN && k < T_SEQ) {
        float d;
        if (k == 0) {
          d = 3.f*(wtr[0]-wsr[0]) + 2.f*(wtr[1]-wsr[1]) + (wtr[2]-wsr[2]);
        } else if (k == T_SEQ-1) {
          d = 3.f*(wtr[T_SEQ-1]-wsr[T_SEQ-1]) + 2.f*(wtr[T_SEQ-2]-wsr[T_SEQ-2])
              + (wtr[T_SEQ-3]-wsr[T_SEQ-3]);
        } else {
          int lo = (k-2 < 0) ? 0 : k-2;
          int hi = (k+2 > T_SEQ-1) ? T_SEQ-1 : k+2;
          d = 0.f;
          for (int t = lo; t <= hi; ++t) d += wtr[t]-wsr[t];
        }
        val = wsr[k] + 0.2f*d;
      }
      pk.u[j] = f2bf(val);
    }
    const int m16 = p >> 4;
    const int l16 = p & 15;
    *(s16x8*)&apack[(size_t)(((m16*NKT + kt) * 64) + lg*16 + l16) * 8] = pk.v;
  }
  if (tid == 0 && p < P_LEN) bias[p] = bs[p] + bt[p];
}

// O[b,p,c] = relu( sum_k Weff[p,k] * X[b,k,c] + bias[p] )
// Block = (batch, 112-col slice) x ALL 768 p-rows; x staged to LDS once
// (one barrier), then 3 m-pairs x 11 kt. R12 change vs R10: the kt loop is
// explicitly software-pipelined -- A-fragments for kt+1 prefetched into named
// registers, all 7 B-fragments read into a live array, and a sched_barrier
// between loads and the 14-MFMA cluster stops the compiler from
// re-serializing into minimal-register load-use pairs (R10: VGPR=64 => JIT
// issue, 120cy LDS latency per 2 MFMAs, MfmaUtil 13%).
__global__ __launch_bounds__(512, 4) void gemm_kernel(
    const float* __restrict__ x, const unsigned short* __restrict__ apack,
    const float* __restrict__ bias, float* __restrict__ out) {
  __shared__ __align__(16) unsigned short Bp[CTILE * BPITCH];   // 80640 B

  const int bid = blockIdx.x;
  const int xcd = bid & 7;
  const int ct  = (xcd << 1) | ((bid >> 3) & 1);  // XCD k owns adjacent ct {2k,2k+1}
  const int b   = bid >> 4;
  const int c0  = ct * CTILE;

  const int tid  = threadIdx.x;
  const int lane = tid & 63;
  const int wid  = tid >> 6;      // 0..7
  const int l16  = lane & 15;
  const int lg   = lane >> 4;

  const float* xb = x + (size_t)b * T_SEQ * C_LEN;
  const s16x8* ap = (const s16x8*)apack;

  // ---- stage x panel: fp32 -> bf16, transposed to [c][k], pitch 360 ----
  for (int i = tid; i < 42 * 56; i += 512) {
    const int cp = i % 56;
    const int kg = i / 56;
    int c = c0 + cp * 2; if (c > C_LEN - 2) c = C_LEN - 2;  // junk masked at store
    float2 v[8];
#pragma unroll
    for (int j = 0; j < 8; ++j)
      v[j] = *(const float2*)(xb + (size_t)(kg * 8 + j) * C_LEN + c);
    union { s16x8 vv; uint32_t dw[4]; } pa, pb;
#pragma unroll
    for (int h = 0; h < 4; ++h) {
      uint32_t ra, rb;
      asm("v_cvt_pk_bf16_f32 %0, %1, %2" : "=v"(ra) : "v"(v[2*h].x), "v"(v[2*h+1].x));
      asm("v_cvt_pk_bf16_f32 %0, %1, %2" : "=v"(rb) : "v"(v[2*h].y), "v"(v[2*h+1].y));
      pa.dw[h] = ra; pb.dw[h] = rb;
    }
    *(s16x8*)&Bp[(cp * 2)     * BPITCH + kg * 8] = pa.vv;
    *(s16x8*)&Bp[(cp * 2 + 1) * BPITCH + kg * 8] = pb.vv;
  }
  // zero k-tail 336..359 (kt=10 reads k up to 351)
  {
    const s16x8 z = {};
    for (int i = tid; i < CTILE * 3; i += 512)
      *(s16x8*)&Bp[(i / 3) * BPITCH + T_SEQ + (i % 3) * 8] = z;
  }
  __syncthreads();   // the only barrier

  const size_t ob = (size_t)b * P_LEN * C_LEN;

#pragma unroll 1
  for (int mp = 0; mp < 3; ++mp) {
    const int m16a = mp * 16 + wid * 2;     // covers 0..47 over (mp, wid, m)
    float bv[2][4];
#pragma unroll
    for (int m = 0; m < 2; ++m) {
      const int pb0 = (m16a + m) * 16 + lg * 4;
#pragma unroll
      for (int r = 0; r < 4; ++r)
        bv[m][r] = (pb0 + r < P_LEN) ? bias[pb0 + r] : 0.f;
    }

    f32x4 acc[2][7] = {};
    s16x8 afc0 = ap[(size_t)((m16a)     * NKT) * 64 + lane];
    s16x8 afc1 = ap[(size_t)((m16a + 1) * NKT) * 64 + lane];

#pragma unroll
    for (int kt = 0; kt < NKT; ++kt) {
      // prefetch A(kt+1): consumed next iteration -> liveness forced
      s16x8 afn0, afn1;
      if (kt + 1 < NKT) {
        afn0 = ap[(size_t)((m16a)     * NKT + kt + 1) * 64 + lane];
        afn1 = ap[(size_t)((m16a + 1) * NKT + kt + 1) * 64 + lane];
      }
      // all 7 B-fragments issued before any MFMA
      s16x8 bf[7];
#pragma unroll
      for (int n = 0; n < 7; ++n)
        bf[n] = *(const s16x8*)&Bp[(n * 16 + l16) * BPITCH + kt * 32 + lg * 8];
      __builtin_amdgcn_sched_barrier(0);   // loads stay above, MFMAs below
#pragma unroll
      for (int n = 0; n < 7; ++n) {
        acc[0][n] = __builtin_amdgcn_mfma_f32_16x16x32_bf16(
            afc0, bf[n], acc[0][n], 0, 0, 0);
        acc[1][n] = __builtin_amdgcn_mfma_f32_16x16x32_bf16(
            afc1, bf[n], acc[1][n], 0, 0, 0);
      }
      if (kt + 1 < NKT) { afc0 = afn0; afc1 = afn1; }
    }

    // epilogue: bias + relu + masked store. C/D: row = lg*4 + r, col = l16
#pragma unroll
    for (int m = 0; m < 2; ++m) {
      const int m16 = m16a + m;
      if (m16 < 45) {               // p < 720, uniform per fragment
        const int pb0 = m16 * 16 + lg * 4;
#pragma unroll
        for (int n = 0; n < 7; ++n) {
          const int cc = c0 + n * 16 + l16;
          if (cc < C_LEN) {
#pragma unroll
            for (int r = 0; r < 4; ++r) {
              float vv = acc[m][n][r] + bv[m][r];
              out[ob + (size_t)(pb0 + r) * C_LEN + cc] = fmaxf(vv, 0.f);
            }
          }
        }
      }
    }
  }
}

extern "C" void kernel_launch(void* const* d_in, const int* in_sizes, int n_in,
                              void* d_out, int out_size, void* d_ws, size_t ws_size,
                              hipStream_t stream) {
  (void)in_sizes; (void)n_in; (void)out_size; (void)ws_size;
  const float* x  = (const float*)d_in[0];
  const float* Ws = (const float*)d_in[1];
  const float* bs = (const float*)d_in[2];
  const float* Wt = (const float*)d_in[3];
  const float* bt = (const float*)d_in[4];
  float* out = (float*)d_out;

  // ws: Apack (48*11 blocks * 1KB = 540672 B) then bias (720 f32)
  unsigned short* apack = (unsigned short*)d_ws;
  float* biasp = (float*)((char*)d_ws + (size_t)NM16 * NKT * 1024);

  prep_w<<<dim3(768), dim3(64), 0, stream>>>(Ws, bs, Wt, bt, apack, biasp);
  gemm_kernel<<<dim3(NB * NCT), dim3(512), 0, stream>>>(x, apack, biasp, out);
}

// Round 13
// 172.486 us; speedup vs baseline: 1.8790x; 1.1358x over previous
//
#include <hip/hip_runtime.h>
#include <hip/hip_bf16.h>
#include <stdint.h>

#define T_SEQ 336
#define NKT   11        // K-tiles of 32 (336 -> 352; tail zeroed in LDS, apack zero-padded)
#define P_LEN 720
#define NM16  48        // 16-row p-blocks in apack (768 rows, zero-padded)
#define C_LEN 1782
#define NB    64
#define CTILE 96        // cols per block: 96 floats = 3 x 128B lines (line-aligned tiles)
#define NCT   19        // ceil(1782/96); last tile masked
#define NFR   6         // 16-col fragments per tile
#define BPITCH 360      // LDS row pitch (bf16); 96*720B = 69120 B -> 2 blocks/CU

typedef __attribute__((ext_vector_type(4))) float f32x4;
typedef __attribute__((ext_vector_type(8))) short s16x8;

__device__ __forceinline__ unsigned short f2bf(float f) {
  unsigned int u = __builtin_bit_cast(unsigned int, f);
  u += 0x7FFFu + ((u >> 16) & 1u);   // RNE
  return (unsigned short)(u >> 16);
}

// Weff[p,k] = Ws[p,k] + 0.2*sum_{t in win(k)} (Wt-Ws)[p,t], packed in MFMA
// fragment order: block m16*NKT+kt holds 64 lanes x 16B; lane lg*16+l16
// carries W[m16*16+l16][kt*32+lg*8+j], j=0..7. Zero-padded p>=720, k>=336.
__global__ __launch_bounds__(64) void prep_w(
    const float* __restrict__ Ws, const float* __restrict__ bs,
    const float* __restrict__ Wt, const float* __restrict__ bt,
    unsigned short* __restrict__ apack, float* __restrict__ bias) {
  const int p   = blockIdx.x;          // 0..767
  const int tid = threadIdx.x;         // 0..63
  if (tid < NKT * 4) {
    const int kt = tid >> 2;
    const int lg = tid & 3;
    const float* wsr = Ws + (size_t)p * T_SEQ;
    const float* wtr = Wt + (size_t)p * T_SEQ;
    union { s16x8 v; unsigned short u[8]; } pk;
#pragma unroll
    for (int j = 0; j < 8; ++j) {
      const int k = kt * 32 + lg * 8 + j;
      float val = 0.f;
      if (p < P_LEN && k < T_SEQ) {
        float d;
        if (k == 0) {
          d = 3.f*(wtr[0]-wsr[0]) + 2.f*(wtr[1]-wsr[1]) + (wtr[2]-wsr[2]);
        } else if (k == T_SEQ-1) {
          d = 3.f*(wtr[T_SEQ-1]-wsr[T_SEQ-1]) + 2.f*(wtr[T_SEQ-2]-wsr[T_SEQ-2])
              + (wtr[T_SEQ-3]-wsr[T_SEQ-3]);
        } else {
          int lo = (k-2 < 0) ? 0 : k-2;
          int hi = (k+2 > T_SEQ-1) ? T_SEQ-1 : k+2;
          d = 0.f;
          for (int t = lo; t <= hi; ++t) d += wtr[t]-wsr[t];
        }
        val = wsr[k] + 0.2f*d;
      }
      pk.u[j] = f2bf(val);
    }
    const int m16 = p >> 4;
    const int l16 = p & 15;
    *(s16x8*)&apack[(size_t)(((m16*NKT + kt) * 64) + lg*16 + l16) * 8] = pk.v;
  }
  if (tid == 0 && p < P_LEN) bias[p] = bs[p] + bt[p];
}

// O[b,p,c] = relu( sum_k Weff[p,k] * X[b,k,c] + bias[p] )
// Block = (batch, 96-col line-aligned slice) x ALL 768 p-rows; x staged to
// LDS once (one barrier), then 3 m-pairs x 11 kt. R13: OPERAND-SWAPPED MFMA
// -- acc = mfma(xfrag, wfrag): D[c][p], lane holds 4 CONSECUTIVE c values ->
// epilogue is one global_store_dwordx4 per fragment (42 wide stores/thread
// instead of 168 scalar dwords).
__global__ __launch_bounds__(512, 4) void gemm_kernel(
    const float* __restrict__ x, const unsigned short* __restrict__ apack,
    const float* __restrict__ bias, float* __restrict__ out) {
  __shared__ __align__(16) unsigned short Bp[CTILE * BPITCH];   // 69120 B

  // 1216 = 8 XCD x 152; XCD x hosts b in [x*8, x*8+8): same-b blocks share L2
  const int bid = blockIdx.x;
  const int swz = (bid & 7) * 152 + (bid >> 3);
  const int b   = swz / NCT;
  const int ct  = swz % NCT;
  const int c0  = ct * CTILE;

  const int tid  = threadIdx.x;
  const int lane = tid & 63;
  const int wid  = tid >> 6;      // 0..7
  const int l16  = lane & 15;
  const int lg   = lane >> 4;

  const float* xb = x + (size_t)b * T_SEQ * C_LEN;
  const s16x8* ap = (const s16x8*)apack;

  // ---- stage x panel: fp32 -> bf16, transposed to [c][k], pitch 360 ----
  for (int i = tid; i < 42 * 48; i += 512) {
    const int cp = i % 48;
    const int kg = i / 48;
    int c = c0 + cp * 2; if (c > C_LEN - 2) c = C_LEN - 2;  // dup masked at store
    float2 v[8];
#pragma unroll
    for (int j = 0; j < 8; ++j)
      v[j] = *(const float2*)(xb + (size_t)(kg * 8 + j) * C_LEN + c);
    union { s16x8 vv; uint32_t dw[4]; } pa, pb;
#pragma unroll
    for (int h = 0; h < 4; ++h) {
      uint32_t ra, rb;
      asm("v_cvt_pk_bf16_f32 %0, %1, %2" : "=v"(ra) : "v"(v[2*h].x), "v"(v[2*h+1].x));
      asm("v_cvt_pk_bf16_f32 %0, %1, %2" : "=v"(rb) : "v"(v[2*h].y), "v"(v[2*h+1].y));
      pa.dw[h] = ra; pb.dw[h] = rb;
    }
    *(s16x8*)&Bp[(cp * 2)     * BPITCH + kg * 8] = pa.vv;
    *(s16x8*)&Bp[(cp * 2 + 1) * BPITCH + kg * 8] = pb.vv;
  }
  // zero k-tail 336..359 (kt=10 reads k up to 351)
  {
    const s16x8 z = {};
    for (int i = tid; i < CTILE * 3; i += 512)
      *(s16x8*)&Bp[(i / 3) * BPITCH + T_SEQ + (i % 3) * 8] = z;
  }
  __syncthreads();   // the only barrier

  const size_t ob = (size_t)b * P_LEN * C_LEN;

#pragma unroll 1
  for (int mp = 0; mp < 3; ++mp) {
    const int m16a = mp * 16 + wid * 2;     // covers 0..47 over (mp, wid, m)

    f32x4 acc[2][NFR] = {};
    s16x8 afc0 = ap[(size_t)((m16a)     * NKT) * 64 + lane];
    s16x8 afc1 = ap[(size_t)((m16a + 1) * NKT) * 64 + lane];

#pragma unroll
    for (int kt = 0; kt < NKT; ++kt) {
      s16x8 afn0, afn1;
      if (kt + 1 < NKT) {
        afn0 = ap[(size_t)((m16a)     * NKT + kt + 1) * 64 + lane];
        afn1 = ap[(size_t)((m16a + 1) * NKT + kt + 1) * 64 + lane];
      }
      s16x8 bf[NFR];
#pragma unroll
      for (int n = 0; n < NFR; ++n)
        bf[n] = *(const s16x8*)&Bp[(n * 16 + l16) * BPITCH + kt * 32 + lg * 8];
      __builtin_amdgcn_sched_barrier(0);
      // operand-swapped: D[c][p] (col=l16 -> p, row=lg*4+r -> c)
#pragma unroll
      for (int n = 0; n < NFR; ++n) {
        acc[0][n] = __builtin_amdgcn_mfma_f32_16x16x32_bf16(
            bf[n], afc0, acc[0][n], 0, 0, 0);
        acc[1][n] = __builtin_amdgcn_mfma_f32_16x16x32_bf16(
            bf[n], afc1, acc[1][n], 0, 0, 0);
      }
      if (kt + 1 < NKT) { afc0 = afn0; afc1 = afn1; }
    }

    // epilogue: bias + relu + dwordx4 stores (lane = 4 consecutive c)
#pragma unroll
    for (int m = 0; m < 2; ++m) {
      const int m16 = m16a + m;
      if (m16 < 45) {                         // p < 720, uniform per fragment
        const float bvm = bias[m16 * 16 + l16];
        float* rowp = out + ob + (size_t)(m16 * 16 + l16) * C_LEN;
#pragma unroll
        for (int n = 0; n < NFR; ++n) {
          const int cb = c0 + n * 16 + lg * 4;
          f32x4 v;
#pragma unroll
          for (int r = 0; r < 4; ++r) v[r] = fmaxf(acc[m][n][r] + bvm, 0.f);
          if (cb + 3 < C_LEN) {
            *(f32x4*)(rowp + cb) = v;
          } else {
#pragma unroll
            for (int r = 0; r < 4; ++r)
              if (cb + r < C_LEN) rowp[cb + r] = v[r];
          }
        }
      }
    }
  }
}

extern "C" void kernel_launch(void* const* d_in, const int* in_sizes, int n_in,
                              void* d_out, int out_size, void* d_ws, size_t ws_size,
                              hipStream_t stream) {
  (void)in_sizes; (void)n_in; (void)out_size; (void)ws_size;
  const float* x  = (const float*)d_in[0];
  const float* Ws = (const float*)d_in[1];
  const float* bs = (const float*)d_in[2];
  const float* Wt = (const float*)d_in[3];
  const float* bt = (const float*)d_in[4];
  float* out = (float*)d_out;

  // ws: Apack (48*11 blocks * 1KB = 540672 B) then bias (720 f32)
  unsigned short* apack = (unsigned short*)d_ws;
  float* biasp = (float*)((char*)d_ws + (size_t)NM16 * NKT * 1024);

  prep_w<<<dim3(768), dim3(64), 0, stream>>>(Ws, bs, Wt, bt, apack, biasp);
  gemm_kernel<<<dim3(NB * NCT), dim3(512), 0, stream>>>(x, apack, biasp, out);
}